// Round 1
// baseline (657.498 us; speedup 1.0000x reference)
//
#include <hip/hip_runtime.h>
#include <cstdint>

// Problem constants (fixed by setup_inputs: H=480, W=1024, S=32, margin=10, step=4)
#define HH 480
#define WW 1024
#define SS 32
#define HW (HH*WW)              // 491520
#define MARGIN 10
#define STEP 4
#define GYC 116                 // len(arange(10, 471, 4))
#define GXC 252                 // len(arange(10, 1015, 4))
#define GG (GYC*GXC)            // 29232 grid candidates
#define NSLOT (2*HH*WW/(STEP*STEP))  // 61440 trajectory slots
#define NBLK (NSLOT/256)        // 240 blocks -> co-resident on 256 CUs
#define NWAVE (NSLOT/64)        // 960 waves
#define CW ((GG+63)/64)         // 457 candidate bitmap words
#define CWP 512                 // padded word count (per-block scan width)

// Agent-scope (device-coherent, L2-bypass) accessors: fresh across XCDs with
// NO cache-maintenance ops (no buffer_wbl2/buffer_inv -> L2 stays warm).
__device__ __forceinline__ unsigned int aload(const unsigned int* p) {
  return __hip_atomic_load(p, __ATOMIC_RELAXED, __HIP_MEMORY_SCOPE_AGENT);
}
__device__ __forceinline__ void astore(unsigned int* p, unsigned int v) {
  __hip_atomic_store(p, v, __ATOMIC_RELAXED, __HIP_MEMORY_SCOPE_AGENT);
}
__device__ __forceinline__ unsigned long long aload64(const unsigned long long* p) {
  return __hip_atomic_load(p, __ATOMIC_RELAXED, __HIP_MEMORY_SCOPE_AGENT);
}
__device__ __forceinline__ void astore64(unsigned long long* p, unsigned long long v) {
  __hip_atomic_store(p, v, __ATOMIC_RELAXED, __HIP_MEMORY_SCOPE_AGENT);
}

__device__ __forceinline__ int clampi(int v, int lo, int hi) {
  return v < lo ? lo : (v > hi ? hi : v);
}

// Fence-free grid barrier with 8-way striped counters (one per 256B line).
// Safe: all 240 blocks co-resident; all cross-block data uses agent-scope
// bypass ops, globally visible once vmcnt drains — and __syncthreads emits
// s_waitcnt vmcnt(0) before s_barrier, so stores precede the arrival bump.
__device__ __forceinline__ void grid_barrier(int* bar, int target) {
  __syncthreads();
  if (threadIdx.x < 64) {
    if (threadIdx.x == 0)
      __hip_atomic_fetch_add(&bar[(blockIdx.x & 7) << 6], 1,
                             __ATOMIC_RELAXED, __HIP_MEMORY_SCOPE_AGENT);
    const int lane = threadIdx.x;
    for (;;) {
      int v = (lane < 8)
            ? __hip_atomic_load(&bar[lane << 6], __ATOMIC_RELAXED, __HIP_MEMORY_SCOPE_AGENT)
            : 0;
      v += __shfl_xor(v, 1, 64);
      v += __shfl_xor(v, 2, 64);
      v += __shfl_xor(v, 4, 64);     // lanes 0..7 summed within the 8-group
      if (__shfl(v, 0, 64) >= target) break;
      __builtin_amdgcn_s_sleep(1);
    }
  }
  __syncthreads();
}

// ---------------------------------------------------------------------------
// K0: zero occ grid + the 8 barrier stripes (ws is poisoned 0xAA).
// ---------------------------------------------------------------------------
__global__ __launch_bounds__(256) void k_init(unsigned int* __restrict__ occ,
                                              int* __restrict__ bar)
{
  int idx = blockIdx.x * 256 + threadIdx.x;
  if (idx < 512) bar[idx] = 0;
  if (idx < GG) occ[idx] = 0u;
}

// ---------------------------------------------------------------------------
// On-the-fly fwd-bwd consistency bit at an integer pixel (px,py) whose forward
// flow (fx,fy) the caller already loaded. Bit-identical to the former k_prune:
// same fp contract(off) arithmetic, same clamping, same threshold compare.
// ---------------------------------------------------------------------------
__device__ __forceinline__ float prune_bit(float px, float py, float fx, float fy,
                                           const float* __restrict__ b0,
                                           const float* __restrict__ b1)
{
#pragma clang fp contract(off)
  float xt = px + fx;
  float yt = py + fy;
  float x0 = floorf(xt), y0 = floorf(yt);
  float wx1 = xt - x0, wx0 = 1.0f - wx1;
  float wy1 = yt - y0, wy0 = 1.0f - wy1;
  int x0i = clampi((int)x0, 0, WW - 1);
  int x1i = x0i + 1; if (x1i > WW - 1) x1i = WW - 1;
  int y0i = clampi((int)y0, 0, HH - 1);
  int y1i = y0i + 1; if (y1i > HH - 1) y1i = HH - 1;
  float w00 = wy0 * wx0, w01 = wy0 * wx1, w10 = wy1 * wx0, w11 = wy1 * wx1;
  int i00 = y0i * WW + x0i, i01 = y0i * WW + x1i;
  int i10 = y1i * WW + x0i, i11 = y1i * WW + x1i;
  float bw0 = ((b0[i00] * w00 + b0[i01] * w01) + b0[i10] * w10) + b0[i11] * w11;
  float bw1 = ((b1[i00] * w00 + b1[i01] * w01) + b1[i10] * w10) + b1[i11] * w11;
  float t0 = fx + bw0, t1 = fy + bw1;
  float diff = sqrtf(t0 * t0 + t1 * t1);
  float magf = sqrtf(fx * fx + fy * fy);
  float magb = sqrtf(bw0 * bw0 + bw1 * bw1);
  float mag = 0.5f * (magf + magb);
  return (diff <= 0.01f * mag + 0.1f) ? 1.0f : 0.0f;
}

// ---------------------------------------------------------------------------
// K1: persistent scan — all 31 steps, TWO grid barriers per step.
//   A: advect + FUSED prune (consistency mask evaluated only at the 4 tap
//      pixels each active slot actually samples — the former k_prune computed
//      it for all 15.2M pixels; only ~3.7M taps are ever consumed) +
//      occ marks (u32 bypass stores); publish per-wave slot-free counts
//      (parity-buffered)                                      -> barrier
//   B: candidate waves ballot occ -> u64 bitmap word (bypass store),
//      self-zero occ for next step                            -> barrier
//   CD: every block loads the 457-word bitmap into LDS, builds the popcount
//       prefix locally (shuffle scan), births = LDS binary search by rank.
// Stable order = word asc, bit asc = index asc (matches reference argsort).
// ---------------------------------------------------------------------------
__global__ __launch_bounds__(256, 1) void k_steps(
    const float* __restrict__ ff, const float* __restrict__ fbk,
    float* __restrict__ X, float* __restrict__ Y, float* __restrict__ Start,
    unsigned int* __restrict__ occ, unsigned long long* __restrict__ bitmap,
    unsigned int* __restrict__ wtot_s, int* bar)
{
#pragma clang fp contract(off)
  const int tid = blockIdx.x * 256 + threadIdx.x;   // slot id
  const int w = tid >> 6;                            // global wave id
  const int lane = tid & 63;
  const int wv = threadIdx.x >> 6;                   // wave-in-block 0..3
  const unsigned long long ltmask = (1ull << lane) - 1ull;

  __shared__ unsigned long long wds[CWP];   // bitmap copy (4 KB)
  __shared__ unsigned int pref[CWP];        // inclusive popcount prefix (2 KB)
  __shared__ int wsum[4];

  float x = 0.f, y = 0.f, st = -1.f;
  if (tid < GG) {
    int ii = tid / GXC, jj = tid - ii * GXC;
    x = (float)(MARGIN + STEP * jj);
    y = (float)(MARGIN + STEP * ii);
    st = 0.f;
  }
  X[tid] = x; Y[tid] = y;   // row 0

  int btarget = 0;

  for (int s = 0; s < SS - 1; ++s) {
    const float* f0 = ff + (size_t)s * 2 * HW;
    const float* f1 = f0 + HW;
    const float* b0 = fbk + (size_t)s * 2 * HW;
    const float* b1 = b0 + HW;

    // ---- Phase A: advect + fused prune + occ marking + slot-free count ----
    if (st >= 0.0f) {
      float xf = floorf(x), yf = floorf(y);
      float wx1 = x - xf, wx0 = 1.0f - wx1;
      float wy1 = y - yf, wy0 = 1.0f - wy1;
      int x0i = clampi((int)xf, 0, WW - 1);
      int x1i = x0i + 1; if (x1i > WW - 1) x1i = WW - 1;
      int y0i = clampi((int)yf, 0, HH - 1);
      int y1i = y0i + 1; if (y1i > HH - 1) y1i = HH - 1;
      float w00 = wy0 * wx0, w01 = wy0 * wx1, w10 = wy1 * wx0, w11 = wy1 * wx1;
      int i00 = y0i * WW + x0i, i01 = y0i * WW + x1i;
      int i10 = y1i * WW + x0i, i11 = y1i * WW + x1i;
      // forward flow at the 4 taps (round 1 of gathers — also the prune inputs)
      float fa00 = f0[i00], fa01 = f0[i01], fa10 = f0[i10], fa11 = f0[i11];
      float fb00 = f1[i00], fb01 = f1[i01], fb10 = f1[i10], fb11 = f1[i11];
      float u = ((fa00 * w00 + fa01 * w01) + fa10 * w10) + fa11 * w11;
      float v = ((fb00 * w00 + fb01 * w01) + fb10 * w10) + fb11 * w11;
      float xt = x + u, yt = y + v;
      bool marg = (xt > (float)MARGIN) && (yt > (float)MARGIN) &&
                  (xt < (float)(WW - MARGIN)) && (yt < (float)(HH - MARGIN));
      // fused prune at the 4 taps (round 2 of gathers: 32 independent loads)
      float o00 = prune_bit((float)x0i, (float)y0i, fa00, fb00, b0, b1);
      float o01 = prune_bit((float)x1i, (float)y0i, fa01, fb01, b0, b1);
      float o10 = prune_bit((float)x0i, (float)y1i, fa10, fb10, b0, b1);
      float o11 = prune_bit((float)x1i, (float)y1i, fa11, fb11, b0, b1);
      float fb = ((o00 * w00 + o01 * w01) + o10 * w10) + o11 * w11;
      bool choose = marg && (fb > 0.5f);
      if (choose) {
        x = xt; y = yt;
        int oy = (int)yt, ox = (int)xt;   // trunc == floor (positive)
        int i0 = ((oy - (MARGIN + 2) + 4099) >> 2) - 1024;  // ceil((oy-12)/4)
        int i1 = ((oy - (MARGIN - 2) + 4096) >> 2) - 1024;  // floor((oy-8)/4)
        int j0 = ((ox - (MARGIN + 2) + 4099) >> 2) - 1024;
        int j1 = ((ox - (MARGIN - 2) + 4096) >> 2) - 1024;
        if (i0 < 0) i0 = 0; if (i1 > GYC - 1) i1 = GYC - 1;
        if (j0 < 0) j0 = 0; if (j1 > GXC - 1) j1 = GXC - 1;
        for (int i = i0; i <= i1; ++i)
          for (int j = j0; j <= j1; ++j)
            astore(&occ[i * GXC + j], 1u);   // same-value stores: benign race
      } else {
        st = -1.0f; x = 0.f; y = 0.f;
      }
    }
    unsigned long long smask = __ballot(st < 0.0f);
    if (lane == 0)
      astore(&wtot_s[(s & 1) * NWAVE + w], (unsigned int)__popcll(smask));
    grid_barrier(bar, btarget += NBLK);

    // ---- Phase B: compress occ -> bitmap, self-zero occ ----
    if (w < CW) {
      int g = w * 64 + lane;
      bool fr = (g < GG) && (aload(&occ[g]) == 0u);
      unsigned long long cm = __ballot(fr);
      if (lane == 0) astore64(&bitmap[w], cm);
      if (g < GG) astore(&occ[g], 0u);       // reset for next step's marks
    }
    grid_barrier(bar, btarget += NBLK);

    // ---- Phase CD: block-local prefix over the bitmap + births ----
    {
      int t = threadIdx.x;
      int e0 = 2 * t, e1 = 2 * t + 1;
      unsigned long long m0 = (e0 < CW) ? aload64(&bitmap[e0]) : 0ull;
      unsigned long long m1 = (e1 < CW) ? aload64(&bitmap[e1]) : 0ull;
      wds[e0] = m0; wds[e1] = m1;
      int p0 = __popcll(m0), p1 = __popcll(m1);
      int v = p0 + p1;
      for (int o = 1; o < 64; o <<= 1) {
        int uu = __shfl_up(v, o, 64);
        if (lane >= o) v += uu;
      }
      if (lane == 63) wsum[wv] = v;
      __syncthreads();
      int base = 0;
      for (int j2 = 0; j2 < wv; ++j2) base += wsum[j2];
      pref[e0] = (unsigned int)(base + v - p1);
      pref[e1] = (unsigned int)(base + v);
      __syncthreads();
    }
    int tc = (int)pref[CWP - 1];              // total free candidates

    // slot-rank prefix: sum of wtot_s over waves < w (parity buffer)
    int ps;
    {
      const unsigned int* ws = wtot_s + (s & 1) * NWAVE;
      int acc = 0;
      for (int j = lane; j < NWAVE; j += 64) {
        unsigned int v2 = aload(&ws[j]);
        if (j < w) acc += (int)v2;
      }
      for (int o = 32; o > 0; o >>= 1) acc += __shfl_xor(acc, o, 64);
      ps = acc;
    }

    if (st < 0.0f) {
      int r = ps + __popcll(smask & ltmask);
      if (r < tc) {                  // r < min(num_cand, num_free) <=> r < num_cand
        // word k containing rank r: largest k with pref[k-1] <= r
        int k = 0;
        for (int b = 256; b >= 1; b >>= 1) {
          int nk = k + b;
          if (nk <= CWP - 1 && (int)pref[nk - 1] <= r) k = nk;
        }
        int j = r - (k ? (int)pref[k - 1] : 0);
        unsigned long long m = wds[k];
        int lo = 0;                  // position of the (j+1)-th set bit
        for (int b = 32; b >= 1; b >>= 1) {
          int nb = lo + b;
          unsigned long long mask = (nb >= 64) ? ~0ull : ((1ull << nb) - 1ull);
          if (__popcll(m & mask) <= j) lo = nb;
        }
        int g = k * 64 + lo;
        int ii = g / GXC, jj = g - ii * GXC;
        x = (float)(MARGIN + STEP * jj);
        y = (float)(MARGIN + STEP * ii);
        st = (float)(s + 1);
      }
    }
    X[(size_t)(s + 1) * NSLOT + tid] = x;
    Y[(size_t)(s + 1) * NSLOT + tid] = y;
  }

  Start[tid] = st;
}

// ---------------------------------------------------------------------------
extern "C" void kernel_launch(void* const* d_in, const int* in_sizes, int n_in,
                              void* d_out, int out_size, void* d_ws, size_t ws_size,
                              hipStream_t stream) {
  const float* ff  = (const float*)d_in[0];   // (1,S,2,H,W)
  const float* fbk = (const float*)d_in[1];

  float* X     = (float*)d_out;                       // (S, N)
  float* Y     = X + (size_t)SS * NSLOT;              // (S, N)
  float* Start = Y + (size_t)SS * NSLOT;              // (N,)

  unsigned int*       occ    = (unsigned int*)d_ws;                       // GG u32
  unsigned long long* bitmap = (unsigned long long*)(occ + GG);           // CW u64
  unsigned int*       wtot_s = (unsigned int*)(bitmap + CW);              // 2*NWAVE u32
  int*                bar    = (int*)(wtot_s + 2 * NWAVE);                // 512 ints

  k_init<<<(GG + 255) / 256, 256, 0, stream>>>(occ, bar);

  k_steps<<<NBLK, 256, 0, stream>>>(ff, fbk, X, Y, Start,
                                    occ, bitmap, wtot_s, bar);
}

// Round 2
// 638.184 us; speedup vs baseline: 1.0303x; 1.0303x over previous
//
#include <hip/hip_runtime.h>
#include <cstdint>

// Problem constants (fixed by setup_inputs: H=480, W=1024, S=32, margin=10, step=4)
#define HH 480
#define WW 1024
#define SS 32
#define HW (HH*WW)              // 491520
#define MARGIN 10
#define STEP 4
#define GYC 116                 // len(arange(10, 471, 4))
#define GXC 252                 // len(arange(10, 1015, 4))
#define GG (GYC*GXC)            // 29232 grid candidates
#define NSLOT (2*HH*WW/(STEP*STEP))  // 61440 trajectory slots
#define NBLK (NSLOT/256)        // 240 blocks -> co-resident on 256 CUs
#define NWAVE (NSLOT/64)        // 960 waves
#define CW ((GG+63)/64)         // 457 candidate bitmap words
#define CWP 512                 // padded word count (per-block scan width)

// Agent-scope (device-coherent) accessors: fresh across XCDs with no cache
// maintenance ops.
__device__ __forceinline__ unsigned int aload(const unsigned int* p) {
  return __hip_atomic_load(p, __ATOMIC_RELAXED, __HIP_MEMORY_SCOPE_AGENT);
}
__device__ __forceinline__ void astore(unsigned int* p, unsigned int v) {
  __hip_atomic_store(p, v, __ATOMIC_RELAXED, __HIP_MEMORY_SCOPE_AGENT);
}
__device__ __forceinline__ unsigned long long aload64(const unsigned long long* p) {
  return __hip_atomic_load(p, __ATOMIC_RELAXED, __HIP_MEMORY_SCOPE_AGENT);
}
__device__ __forceinline__ void astore64(unsigned long long* p, unsigned long long v) {
  __hip_atomic_store(p, v, __ATOMIC_RELAXED, __HIP_MEMORY_SCOPE_AGENT);
}

__device__ __forceinline__ int clampi(int v, int lo, int hi) {
  return v < lo ? lo : (v > hi ? hi : v);
}

// Fence-free grid barrier with 8-way striped counters (one per 256B line).
// Safe: all 240 blocks co-resident; all cross-block data uses agent-scope
// ops, globally visible once vmcnt drains — and __syncthreads emits
// s_waitcnt vmcnt(0) before s_barrier, so stores precede the arrival bump.
__device__ __forceinline__ void grid_barrier(int* bar, int target) {
  __syncthreads();
  if (threadIdx.x < 64) {
    if (threadIdx.x == 0)
      __hip_atomic_fetch_add(&bar[(blockIdx.x & 7) << 6], 1,
                             __ATOMIC_RELAXED, __HIP_MEMORY_SCOPE_AGENT);
    const int lane = threadIdx.x;
    for (;;) {
      int v = (lane < 8)
            ? __hip_atomic_load(&bar[lane << 6], __ATOMIC_RELAXED, __HIP_MEMORY_SCOPE_AGENT)
            : 0;
      v += __shfl_xor(v, 1, 64);
      v += __shfl_xor(v, 2, 64);
      v += __shfl_xor(v, 4, 64);     // lanes 0..7 summed within the 8-group
      if (__shfl(v, 0, 64) >= target) break;
      __builtin_amdgcn_s_sleep(1);
    }
  }
  __syncthreads();
}

// ---------------------------------------------------------------------------
// K0: zero occ grid + the 8 barrier stripes (ws is poisoned 0xAA).
// ---------------------------------------------------------------------------
__global__ __launch_bounds__(256) void k_init(unsigned int* __restrict__ occ,
                                              int* __restrict__ bar)
{
  int idx = blockIdx.x * 256 + threadIdx.x;
  if (idx < 512) bar[idx] = 0;
  if (idx < GG) occ[idx] = 0u;
}

// ---------------------------------------------------------------------------
// Bilinear footprint at (xs,ys): corner indices + weights. Identical float ops
// to the verified round-1 code (weights from unclipped coords, clamped gathers).
// ---------------------------------------------------------------------------
struct Bil {
  int x0i, x1i, y0i, y1i;
  int i00, i01, i10, i11;
  float w00, w01, w10, w11;
};

__device__ __forceinline__ Bil mkbil(float xs, float ys) {
#pragma clang fp contract(off)
  float x0 = floorf(xs), y0 = floorf(ys);
  float wx1 = xs - x0, wx0 = 1.0f - wx1;
  float wy1 = ys - y0, wy0 = 1.0f - wy1;
  Bil b;
  b.x0i = clampi((int)x0, 0, WW - 1);
  b.x1i = b.x0i + 1 > WW - 1 ? WW - 1 : b.x0i + 1;
  b.y0i = clampi((int)y0, 0, HH - 1);
  b.y1i = b.y0i + 1 > HH - 1 ? HH - 1 : b.y0i + 1;
  b.i00 = b.y0i * WW + b.x0i; b.i01 = b.y0i * WW + b.x1i;
  b.i10 = b.y1i * WW + b.x0i; b.i11 = b.y1i * WW + b.x1i;
  b.w00 = wy0 * wx0; b.w01 = wy0 * wx1;
  b.w10 = wy1 * wx0; b.w11 = wy1 * wx1;
  return b;
}

// Fwd-bwd consistency bit from pre-gathered backward-flow corner values.
// Bit-identical arithmetic to the round-1 prune_bit.
__device__ __forceinline__ float prune_val(float fx, float fy,
    float c00a, float c01a, float c10a, float c11a,
    float c00b, float c01b, float c10b, float c11b, const Bil& t)
{
#pragma clang fp contract(off)
  float bw0 = ((c00a * t.w00 + c01a * t.w01) + c10a * t.w10) + c11a * t.w11;
  float bw1 = ((c00b * t.w00 + c01b * t.w01) + c10b * t.w10) + c11b * t.w11;
  float t0 = fx + bw0, t1 = fy + bw1;
  float diff = sqrtf(t0 * t0 + t1 * t1);
  float magf = sqrtf(fx * fx + fy * fy);
  float magb = sqrtf(bw0 * bw0 + bw1 * bw1);
  float mag = 0.5f * (magf + magb);
  return (diff <= 0.01f * mag + 0.1f) ? 1.0f : 0.0f;
}

// ---------------------------------------------------------------------------
// K1: persistent scan, software-pipelined across the TWO existing grid
// barriers per step (1 wave/SIMD -> no TLP; all latency must hide under the
// barriers' vmcnt drains):
//   A_s:  pure-VALU prune decision from pre-loaded b-values; occ marks;
//         survivors issue the 8 f-tap loads for step s+1     -> barrier 1
//   B_s:  occ ballot -> bitmap + self-zero; pipelined lanes consume f
//         (drained by bar1), compute advected candidate + margin + the 4
//         prune-target footprints, issue 32 b-loads for s+1  -> barrier 2
//   CD_s: bitmap prefix + births. Born slots are at INTEGER grid positions
//         (degenerate weights: only tap00 matters, exactly) — issue their 2
//         f-loads at birth; their first advection runs a short 1-round
//         divergent path at A_{s+1}.
// Stable order = word asc, bit asc = index asc (matches reference argsort).
// ---------------------------------------------------------------------------
__global__ __launch_bounds__(256, 1) void k_steps(
    const float* __restrict__ ff, const float* __restrict__ fbk,
    float* __restrict__ X, float* __restrict__ Y, float* __restrict__ Start,
    unsigned int* __restrict__ occ, unsigned long long* __restrict__ bitmap,
    unsigned int* __restrict__ wtot_s, int* bar)
{
#pragma clang fp contract(off)
  const int tid = blockIdx.x * 256 + threadIdx.x;   // slot id
  const int w = tid >> 6;                            // global wave id
  const int lane = tid & 63;
  const int wv = threadIdx.x >> 6;                   // wave-in-block 0..3
  const unsigned long long ltmask = (1ull << lane) - 1ull;

  __shared__ unsigned long long wds[CWP];   // bitmap copy (4 KB)
  __shared__ unsigned int pref[CWP];        // inclusive popcount prefix (2 KB)
  __shared__ int wsum[4];

  // Slot state. mode: 0 dead, 1 pipelined (pf/pb/pxt valid), 2 fresh at
  // integer position (pf0/pf4 in flight).
  float x = 0.f, y = 0.f, st = -1.f;
  int mode = 0;
  float pf0 = 0.f, pf1 = 0.f, pf2 = 0.f, pf3 = 0.f;   // f0 at taps 00,01,10,11
  float pf4 = 0.f, pf5 = 0.f, pf6 = 0.f, pf7 = 0.f;   // f1 at taps 00,01,10,11
  float pb[32];                                        // b corner values, 8/tap
  float pxt = 0.f, pyt = 0.f;                          // advected candidate
  bool  pmarg = false;

  if (tid < GG) {
    int ii = tid / GXC, jj = tid - ii * GXC;
    int ix = MARGIN + STEP * jj, iy = MARGIN + STEP * ii;
    x = (float)ix; y = (float)iy;
    st = 0.f; mode = 2;
    int p = iy * WW + ix;
    pf0 = ff[p];            // f0[s=0] at the integer start position
    pf4 = ff[HW + p];       // f1[s=0]
  }
  X[tid] = x; Y[tid] = y;   // row 0

// Issue the 32 b-corner loads for tap tt (consumed next iteration's A).
#define ISSUE_TAP(tt, TXI, TYI, FX, FY) do { \
    Bil Bt = mkbil((float)P.TXI + (FX), (float)P.TYI + (FY)); \
    pb[(tt)*8+0] = b0n[Bt.i00]; pb[(tt)*8+1] = b0n[Bt.i01]; \
    pb[(tt)*8+2] = b0n[Bt.i10]; pb[(tt)*8+3] = b0n[Bt.i11]; \
    pb[(tt)*8+4] = b1n[Bt.i00]; pb[(tt)*8+5] = b1n[Bt.i01]; \
    pb[(tt)*8+6] = b1n[Bt.i10]; pb[(tt)*8+7] = b1n[Bt.i11]; \
  } while (0)

// Recompute the identical footprint and fold pre-loaded values into the bit.
#define PRUNE_TAP(tt, TXI, TYI, FX, FY, OUT) do { \
    Bil Bt = mkbil((float)P.TXI + (FX), (float)P.TYI + (FY)); \
    OUT = prune_val((FX), (FY), \
                    pb[(tt)*8+0], pb[(tt)*8+1], pb[(tt)*8+2], pb[(tt)*8+3], \
                    pb[(tt)*8+4], pb[(tt)*8+5], pb[(tt)*8+6], pb[(tt)*8+7], Bt); \
  } while (0)

  int btarget = 0;

  for (int s = 0; s < SS - 1; ++s) {
    const float* b0  = fbk + (size_t)s * 2 * HW;       // this step's bwd flow
    const float* b1  = b0 + HW;
    const float* f0n = ff + (size_t)(s + 1) * 2 * HW;  // NEXT step's fwd flow
    const float* f1n = f0n + HW;

    // ---- Phase A: prune decision (pure VALU for pipelined lanes) ----------
    bool moved = false;
    if (mode == 1) {
      Bil P = mkbil(x, y);
      float o0, o1, o2, o3;
      PRUNE_TAP(0, x0i, y0i, pf0, pf4, o0);
      PRUNE_TAP(1, x1i, y0i, pf1, pf5, o1);
      PRUNE_TAP(2, x0i, y1i, pf2, pf6, o2);
      PRUNE_TAP(3, x1i, y1i, pf3, pf7, o3);
      float fbv = ((o0 * P.w00 + o1 * P.w01) + o2 * P.w10) + o3 * P.w11;
      if (pmarg && fbv > 0.5f) {
        x = pxt; y = pyt;
        Bil Pn = mkbil(x, y);                 // prefetch f for step s+1
        pf0 = f0n[Pn.i00]; pf1 = f0n[Pn.i01]; pf2 = f0n[Pn.i10]; pf3 = f0n[Pn.i11];
        pf4 = f1n[Pn.i00]; pf5 = f1n[Pn.i01]; pf6 = f1n[Pn.i10]; pf7 = f1n[Pn.i11];
        moved = true;
      } else { st = -1.f; x = 0.f; y = 0.f; mode = 0; }
    } else if (mode == 2) {
      // Integer position: weights degenerate exactly (w00=1, rest=0) ->
      // u = f0[p], v = f1[p], fb = o00. Bit-identical to the generic path.
      float u = pf0, v = pf4;
      float xt = x + u, yt = y + v;
      bool marg = (xt > (float)MARGIN) && (yt > (float)MARGIN) &&
                  (xt < (float)(WW - MARGIN)) && (yt < (float)(HH - MARGIN));
      Bil Bt = mkbil(xt, yt);
      float o00 = prune_val(u, v,
                            b0[Bt.i00], b0[Bt.i01], b0[Bt.i10], b0[Bt.i11],
                            b1[Bt.i00], b1[Bt.i01], b1[Bt.i10], b1[Bt.i11], Bt);
      if (marg && o00 > 0.5f) {
        x = xt; y = yt; mode = 1;
        Bil Pn = mkbil(x, y);                 // prefetch f for step s+1
        pf0 = f0n[Pn.i00]; pf1 = f0n[Pn.i01]; pf2 = f0n[Pn.i10]; pf3 = f0n[Pn.i11];
        pf4 = f1n[Pn.i00]; pf5 = f1n[Pn.i01]; pf6 = f1n[Pn.i10]; pf7 = f1n[Pn.i11];
        moved = true;
      } else { st = -1.f; x = 0.f; y = 0.f; mode = 0; }
    }
    if (moved) {
      int oy = (int)y, ox = (int)x;   // trunc == floor (positive)
      int i0 = ((oy - (MARGIN + 2) + 4099) >> 2) - 1024;  // ceil((oy-12)/4)
      int i1 = ((oy - (MARGIN - 2) + 4096) >> 2) - 1024;  // floor((oy-8)/4)
      int j0 = ((ox - (MARGIN + 2) + 4099) >> 2) - 1024;
      int j1 = ((ox - (MARGIN - 2) + 4096) >> 2) - 1024;
      if (i0 < 0) i0 = 0; if (i1 > GYC - 1) i1 = GYC - 1;
      if (j0 < 0) j0 = 0; if (j1 > GXC - 1) j1 = GXC - 1;
      for (int i = i0; i <= i1; ++i)
        for (int j = j0; j <= j1; ++j)
          astore(&occ[i * GXC + j], 1u);   // same-value stores: benign race
    }
    unsigned long long smask = __ballot(st < 0.0f);
    if (lane == 0)
      astore(&wtot_s[(s & 1) * NWAVE + w], (unsigned int)__popcll(smask));
    grid_barrier(bar, btarget += NBLK);    // drains the f-prefetch too

    // ---- Phase B: pipeline issue (f now resident), occ -> bitmap ----------
    if (mode == 1 && s < SS - 2) {
      Bil P = mkbil(x, y);
      float u_ = ((pf0 * P.w00 + pf1 * P.w01) + pf2 * P.w10) + pf3 * P.w11;
      float v_ = ((pf4 * P.w00 + pf5 * P.w01) + pf6 * P.w10) + pf7 * P.w11;
      pxt = x + u_; pyt = y + v_;
      pmarg = (pxt > (float)MARGIN) && (pyt > (float)MARGIN) &&
              (pxt < (float)(WW - MARGIN)) && (pyt < (float)(HH - MARGIN));
      const float* b0n = fbk + (size_t)(s + 1) * 2 * HW;
      const float* b1n = b0n + HW;
      ISSUE_TAP(0, x0i, y0i, pf0, pf4);
      ISSUE_TAP(1, x1i, y0i, pf1, pf5);
      ISSUE_TAP(2, x0i, y1i, pf2, pf6);
      ISSUE_TAP(3, x1i, y1i, pf3, pf7);
    }
    if (w < CW) {
      int g = w * 64 + lane;
      bool fr = (g < GG) && (aload(&occ[g]) == 0u);
      unsigned long long cm = __ballot(fr);
      if (lane == 0) astore64(&bitmap[w], cm);
      if (g < GG) astore(&occ[g], 0u);       // reset for next step's marks
    }
    grid_barrier(bar, btarget += NBLK);    // drains the b-loads too

    // ---- Phase CD: block-local prefix over the bitmap + births ------------
    {
      int t = threadIdx.x;
      int e0 = 2 * t, e1 = 2 * t + 1;
      unsigned long long m0 = (e0 < CW) ? aload64(&bitmap[e0]) : 0ull;
      unsigned long long m1 = (e1 < CW) ? aload64(&bitmap[e1]) : 0ull;
      wds[e0] = m0; wds[e1] = m1;
      int p0 = __popcll(m0), p1 = __popcll(m1);
      int v = p0 + p1;
      for (int o = 1; o < 64; o <<= 1) {
        int uu = __shfl_up(v, o, 64);
        if (lane >= o) v += uu;
      }
      if (lane == 63) wsum[wv] = v;
      __syncthreads();
      int base = 0;
      for (int j2 = 0; j2 < wv; ++j2) base += wsum[j2];
      pref[e0] = (unsigned int)(base + v - p1);
      pref[e1] = (unsigned int)(base + v);
      __syncthreads();
    }
    int tc = (int)pref[CWP - 1];              // total free candidates

    // slot-rank prefix: sum of wtot_s over waves < w (parity buffer)
    int ps;
    {
      const unsigned int* ws = wtot_s + (s & 1) * NWAVE;
      int acc = 0;
      for (int j = lane; j < NWAVE; j += 64) {
        unsigned int v2 = aload(&ws[j]);
        if (j < w) acc += (int)v2;
      }
      for (int o = 32; o > 0; o >>= 1) acc += __shfl_xor(acc, o, 64);
      ps = acc;
    }

    if (st < 0.0f) {
      int r = ps + __popcll(smask & ltmask);
      if (r < tc) {                  // r < min(num_cand, num_free) <=> r < num_cand
        // word k containing rank r: largest k with pref[k-1] <= r
        int k = 0;
        for (int b = 256; b >= 1; b >>= 1) {
          int nk = k + b;
          if (nk <= CWP - 1 && (int)pref[nk - 1] <= r) k = nk;
        }
        int j = r - (k ? (int)pref[k - 1] : 0);
        unsigned long long m = wds[k];
        int lo = 0;                  // position of the (j+1)-th set bit
        for (int b = 32; b >= 1; b >>= 1) {
          int nb = lo + b;
          unsigned long long mask = (nb >= 64) ? ~0ull : ((1ull << nb) - 1ull);
          if (__popcll(m & mask) <= j) lo = nb;
        }
        int g = k * 64 + lo;
        int ii = g / GXC, jj = g - ii * GXC;
        int ix = MARGIN + STEP * jj, iy = MARGIN + STEP * ii;
        x = (float)ix; y = (float)iy;
        st = (float)(s + 1);
        mode = 2;
        int p = iy * WW + ix;
        pf0 = f0n[p];               // issue the born slot's f-loads now
        pf4 = f1n[p];
      }
    }
    X[(size_t)(s + 1) * NSLOT + tid] = x;
    Y[(size_t)(s + 1) * NSLOT + tid] = y;
  }

#undef ISSUE_TAP
#undef PRUNE_TAP

  Start[tid] = st;
}

// ---------------------------------------------------------------------------
extern "C" void kernel_launch(void* const* d_in, const int* in_sizes, int n_in,
                              void* d_out, int out_size, void* d_ws, size_t ws_size,
                              hipStream_t stream) {
  const float* ff  = (const float*)d_in[0];   // (1,S,2,H,W)
  const float* fbk = (const float*)d_in[1];

  float* X     = (float*)d_out;                       // (S, N)
  float* Y     = X + (size_t)SS * NSLOT;              // (S, N)
  float* Start = Y + (size_t)SS * NSLOT;              // (N,)

  unsigned int*       occ    = (unsigned int*)d_ws;                       // GG u32
  unsigned long long* bitmap = (unsigned long long*)(occ + GG);           // CW u64
  unsigned int*       wtot_s = (unsigned int*)(bitmap + CW);              // 2*NWAVE u32
  int*                bar    = (int*)(wtot_s + 2 * NWAVE);                // 512 ints

  k_init<<<(GG + 255) / 256, 256, 0, stream>>>(occ, bar);

  k_steps<<<NBLK, 256, 0, stream>>>(ff, fbk, X, Y, Start,
                                    occ, bitmap, wtot_s, bar);
}